// Round 1
// baseline (74.592 us; speedup 1.0000x reference)
//
#include <hip/hip_runtime.h>
#include <hip/hip_bf16.h>

typedef __bf16 bf16x8 __attribute__((ext_vector_type(8)));
typedef float floatx4 __attribute__((ext_vector_type(4)));

#define BM 128
#define BN 128
#define BK 32
#define EPS 1e-5f

// ---------------- f32 -> bf16 conversion (vectorized, grid-stride) ----------
__global__ void cvt_f32_to_bf16(const float* __restrict__ in,
                                ushort* __restrict__ out, int n4) {
    int i = blockIdx.x * blockDim.x + threadIdx.x;
    int stride = gridDim.x * blockDim.x;
    for (; i < n4; i += stride) {
        float4 v = reinterpret_cast<const float4*>(in)[i];
        ushort4 o;
        __hip_bfloat16 b0 = __float2bfloat16(v.x);
        __hip_bfloat16 b1 = __float2bfloat16(v.y);
        __hip_bfloat16 b2 = __float2bfloat16(v.z);
        __hip_bfloat16 b3 = __float2bfloat16(v.w);
        o.x = __builtin_bit_cast(unsigned short, b0);
        o.y = __builtin_bit_cast(unsigned short, b1);
        o.z = __builtin_bit_cast(unsigned short, b2);
        o.w = __builtin_bit_cast(unsigned short, b3);
        reinterpret_cast<ushort4*>(out)[i] = o;
    }
}

// ---------------- fold BN+scale into per-column alpha/bias ------------------
__global__ void bn_fold(const float* __restrict__ scale,
                        const float* __restrict__ mean,
                        const float* __restrict__ var,
                        const float* __restrict__ gamma,
                        const float* __restrict__ beta,
                        float* __restrict__ alpha,
                        float* __restrict__ bias, int n) {
    int i = blockIdx.x * blockDim.x + threadIdx.x;
    if (i < n) {
        float rs = rsqrtf(var[i] + EPS);
        float g = gamma[i] * rs;
        alpha[i] = scale[i] * g;
        bias[i]  = beta[i] - mean[i] * g;
    }
}

// ---------------- bf16 MFMA GEMM, m97 structure (128x128 tile, BK=32) -------
// C[m][n] = sum_k A[m][k] * B[n][k]   (B stored row-major [N][K] == B^T input)
// epilogue: C = C*alpha[n] + bias[n]
__device__ __forceinline__ void gload_lds16(const void* g, void* l) {
    __builtin_amdgcn_global_load_lds(
        (const __attribute__((address_space(1))) void*)g,
        (__attribute__((address_space(3))) void*)l, 16, 0, 0);
}

__global__ __launch_bounds__(256) void gemm_bf16_bn(
    const ushort* __restrict__ A,   // [M][K] bf16 bits
    const ushort* __restrict__ B,   // [N][K] bf16 bits
    const float* __restrict__ alpha,
    const float* __restrict__ bias,
    float* __restrict__ C, int M, int N, int K) {
    __shared__ ushort As[BM * BK];   // [128][32] linear (global_load_lds dest)
    __shared__ ushort Bs[BN * BK];

    const int tid  = threadIdx.x;
    const int wid  = tid >> 6;
    const int lane = tid & 63;

    const int nTilesN = N / BN;
    const int bm = (int)blockIdx.x / nTilesN;
    const int bn = (int)blockIdx.x % nTilesN;
    const int brow = bm * BM;
    const int bcol = bn * BN;

    // wave sub-tile: 2x2 waves, each 64x64 output
    const int wr = (wid >> 1) * 64;
    const int wc = (wid & 1) * 64;

    floatx4 acc[4][4];
#pragma unroll
    for (int m = 0; m < 4; ++m)
#pragma unroll
        for (int n = 0; n < 4; ++n) acc[m][n] = (floatx4)0.0f;

    // staging: per issue, wave w covers rows [issue*64 + w*16, +16), lane l ->
    // row + l/4, 16B chunk (l%4) within the 64B row. LDS dest is wave-uniform
    // base + lane*16 (hardware), matching linear [row][32] layout.
    const int srow = wid * 16 + (lane >> 2);
    const int scol = (lane & 3) * 8;          // element offset in row
    const ushort* aSrc0 = A + (size_t)(brow + srow) * K + scol;
    const ushort* aSrc1 = A + (size_t)(brow + 64 + srow) * K + scol;
    const ushort* bSrc0 = B + (size_t)(bcol + srow) * K + scol;
    const ushort* bSrc1 = B + (size_t)(bcol + 64 + srow) * K + scol;
    ushort* aDst0 = &As[(size_t)(wid * 16) * BK];
    ushort* aDst1 = &As[(size_t)(64 + wid * 16) * BK];
    ushort* bDst0 = &Bs[(size_t)(wid * 16) * BK];
    ushort* bDst1 = &Bs[(size_t)(64 + wid * 16) * BK];

    const int fr = lane & 15;          // fragment row/col within 16
    const int fk = (lane >> 4) * 8;    // fragment k offset

    const int nK = K / BK;
    for (int kt = 0; kt < nK; ++kt) {
        const int koff = kt * BK;
        gload_lds16(aSrc0 + koff, aDst0);
        gload_lds16(aSrc1 + koff, aDst1);
        gload_lds16(bSrc0 + koff, bDst0);
        gload_lds16(bSrc1 + koff, bDst1);
        __syncthreads();   // compiler emits vmcnt(0) drain before barrier

        bf16x8 af[4], bf[4];
#pragma unroll
        for (int m = 0; m < 4; ++m)
            af[m] = *(const bf16x8*)&As[(size_t)(wr + m * 16 + fr) * BK + fk];
#pragma unroll
        for (int n = 0; n < 4; ++n)
            bf[n] = *(const bf16x8*)&Bs[(size_t)(wc + n * 16 + fr) * BK + fk];

#pragma unroll
        for (int m = 0; m < 4; ++m)
#pragma unroll
            for (int n = 0; n < 4; ++n)
                acc[m][n] = __builtin_amdgcn_mfma_f32_16x16x32_bf16(
                    af[m], bf[n], acc[m][n], 0, 0, 0);
        __syncthreads();
    }

    // epilogue: C/D layout col=lane&15, row=(lane>>4)*4+j  [m89/m91 verified]
    float al[4], bi[4];
    const int ccol = bcol + wc + fr;
#pragma unroll
    for (int n = 0; n < 4; ++n) {
        al[n] = alpha[ccol + n * 16];
        bi[n] = bias[ccol + n * 16];
    }
    const int r0 = brow + wr + (lane >> 4) * 4;
#pragma unroll
    for (int m = 0; m < 4; ++m)
#pragma unroll
        for (int n = 0; n < 4; ++n)
#pragma unroll
            for (int j = 0; j < 4; ++j) {
                int row = r0 + m * 16 + j;
                int col = ccol + n * 16;
                C[(size_t)row * N + col] = acc[m][n][j] * al[n] + bi[n];
            }
}

// ---------------- safety fallback (fp32 vector, naive) ----------------------
__global__ void gemm_f32_naive(const float* __restrict__ A,
                               const float* __restrict__ B,
                               const float* __restrict__ scale,
                               const float* __restrict__ mean,
                               const float* __restrict__ var,
                               const float* __restrict__ gamma,
                               const float* __restrict__ beta,
                               float* __restrict__ C, int N, int K) {
    int o = blockIdx.x * blockDim.x + threadIdx.x;
    int b = blockIdx.y;
    if (o >= N) return;
    float s = 0.f;
    const float* a = A + (size_t)b * K;
    const float* w = B + (size_t)o * K;
    for (int k = 0; k < K; ++k) s += a[k] * w[k];
    float rs = rsqrtf(var[o] + EPS);
    float g = gamma[o] * rs;
    C[(size_t)b * N + o] = s * scale[o] * g + (beta[o] - mean[o] * g);
}

extern "C" void kernel_launch(void* const* d_in, const int* in_sizes, int n_in,
                              void* d_out, int out_size, void* d_ws, size_t ws_size,
                              hipStream_t stream) {
    const float* x     = (const float*)d_in[0];
    const float* w     = (const float*)d_in[1];
    const float* scale = (const float*)d_in[2];
    const float* mean  = (const float*)d_in[3];
    const float* var   = (const float*)d_in[4];
    const float* gamma = (const float*)d_in[5];
    const float* beta  = (const float*)d_in[6];
    float* out = (float*)d_out;

    const int OUT = in_sizes[2];
    const int IN  = in_sizes[1] / OUT;
    const int Bsz = in_sizes[0] / IN;

    const size_t xElems = (size_t)Bsz * IN;
    const size_t wElems = (size_t)OUT * IN;
    const size_t need = xElems * 2 + wElems * 2 + (size_t)OUT * 8;

    const bool tiled_ok = (Bsz % BM == 0) && (OUT % BN == 0) && (IN % BK == 0) &&
                          (ws_size >= need);

    if (!tiled_ok) {
        dim3 grid((OUT + 255) / 256, Bsz);
        gemm_f32_naive<<<grid, 256, 0, stream>>>(x, w, scale, mean, var, gamma,
                                                 beta, out, OUT, IN);
        return;
    }

    ushort* xb = (ushort*)d_ws;
    ushort* wb = xb + xElems;
    float* alpha = (float*)(wb + wElems);
    float* bias  = alpha + OUT;

    cvt_f32_to_bf16<<<2048, 256, 0, stream>>>(x, xb, (int)(xElems / 4));
    cvt_f32_to_bf16<<<2048, 256, 0, stream>>>(w, wb, (int)(wElems / 4));
    bn_fold<<<(OUT + 255) / 256, 256, 0, stream>>>(scale, mean, var, gamma, beta,
                                                   alpha, bias, OUT);

    dim3 grid((Bsz / BM) * (OUT / BN));
    gemm_bf16_bn<<<grid, 256, 0, stream>>>(xb, wb, alpha, bias, out, Bsz, OUT, IN);
}

// Round 2
// 65.268 us; speedup vs baseline: 1.1429x; 1.1429x over previous
//
#include <hip/hip_runtime.h>
#include <hip/hip_bf16.h>

typedef __bf16 bf16x8 __attribute__((ext_vector_type(8)));
typedef float floatx4 __attribute__((ext_vector_type(4)));

#define BM 256
#define BN 128
#define BK 64
#define A_TILE (BM * BK)   // 16384 ushorts = 32 KB
#define B_TILE (BN * BK)   // 8192 ushorts  = 16 KB
#define EPS 1e-5f

// ---------------- f32 -> bf16 conversion (vectorized, grid-stride) ----------
__global__ void cvt_f32_to_bf16(const float* __restrict__ in,
                                ushort* __restrict__ out, int n4) {
    int i = blockIdx.x * blockDim.x + threadIdx.x;
    int stride = gridDim.x * blockDim.x;
    for (; i < n4; i += stride) {
        float4 v = reinterpret_cast<const float4*>(in)[i];
        ushort4 o;
        o.x = __builtin_bit_cast(unsigned short, __float2bfloat16(v.x));
        o.y = __builtin_bit_cast(unsigned short, __float2bfloat16(v.y));
        o.z = __builtin_bit_cast(unsigned short, __float2bfloat16(v.z));
        o.w = __builtin_bit_cast(unsigned short, __float2bfloat16(v.w));
        reinterpret_cast<ushort4*>(out)[i] = o;
    }
}

// ---------------- fold BN+scale into per-column alpha/bias ------------------
__global__ void bn_fold(const float* __restrict__ scale,
                        const float* __restrict__ mean,
                        const float* __restrict__ var,
                        const float* __restrict__ gamma,
                        const float* __restrict__ beta,
                        float* __restrict__ alpha,
                        float* __restrict__ bias, int n) {
    int i = blockIdx.x * blockDim.x + threadIdx.x;
    if (i < n) {
        float rs = rsqrtf(var[i] + EPS);
        float g = gamma[i] * rs;
        alpha[i] = scale[i] * g;
        bias[i]  = beta[i] - mean[i] * g;
    }
}

__device__ __forceinline__ void gload_lds16(const ushort* g, ushort* l) {
    __builtin_amdgcn_global_load_lds(
        (const __attribute__((address_space(1))) void*)g,
        (__attribute__((address_space(3))) void*)l, 16, 0, 0);
}

// ---------------- bf16 MFMA GEMM: 256x128 tile, BK=64, depth-2 pipeline -----
// C[m][n] = sum_k A[m][k]*B[n][k]; epilogue C = C*alpha[n] + bias[n].
//
// Pipeline: 2 LDS buffers, prefetch depth 2, raw s_barrier + counted vmcnt(6)
// (6 global_load_lds per tile per wave stay in flight across barriers).
// Steady state at top of iter kt: outstanding = tile(kt+1)'s 6 loads.
//   COMPUTE(buf[kt&1])            // staged 2 iters ago, fully landed
//   s_barrier                     // all waves done reading buf[kt&1]
//   STAGE(kt+2 -> buf[kt&1])      // outstanding 6 -> 12
//   s_waitcnt vmcnt(6)            // retire tile(kt+1)'s 6; kt+2's stay in flight
//   s_barrier                     // tile kt+1 visible to all waves
//
// LDS swizzle (T2, rule #21 both-sides): logical tile [R][64] bf16, row =
// 128 B = 8 chunks of 16 B. phys chunk = logical chunk ^ (row&7). Staging
// pre-swizzles the GLOBAL source column (global_load_lds writes linearly);
// fragment reads apply the same XOR.
__global__ __launch_bounds__(512, 2) void gemm_bf16_bn(
    const ushort* __restrict__ A,   // [M][K] bf16 bits
    const ushort* __restrict__ B,   // [N][K] bf16 bits
    const float* __restrict__ alpha,
    const float* __restrict__ bias,
    float* __restrict__ C, int M, int N, int K) {
    __shared__ ushort As[2 * A_TILE];   // 64 KB
    __shared__ ushort Bs[2 * B_TILE];   // 32 KB

    const int tid  = threadIdx.x;
    const int wid  = tid >> 6;
    const int lane = tid & 63;

    // bijective XCD-aware block swizzle (m204)
    const int nwg  = (int)gridDim.x;
    const int orig = (int)blockIdx.x;
    const int q = nwg >> 3, rr = nwg & 7;
    const int xcd = orig & 7;
    const int swz = ((xcd < rr) ? xcd * (q + 1) : rr * (q + 1) + (xcd - rr) * q)
                    + (orig >> 3);
    const int nTilesN = N / BN;
    const int brow = (swz / nTilesN) * BM;
    const int bcol = (swz % nTilesN) * BN;

    // 8 waves = 4M x 2N, each owns a 64x64 output sub-tile
    const int wr = (wid >> 1) * 64;
    const int wc = (wid & 1) * 64;
    const int fr = lane & 15;
    const int hi = lane >> 4;

    // fragment LDS offsets (ushort units), loop-invariant, swizzled
    int offA[2][4], offB[2][4];
#pragma unroll
    for (int s = 0; s < 2; ++s) {
#pragma unroll
        for (int m = 0; m < 4; ++m) {
            int row = wr + m * 16 + fr;                  // row&7 == fr&7
            offA[s][m] = row * BK + (((s * 4 + hi) ^ (fr & 7)) * 8);
        }
#pragma unroll
        for (int n = 0; n < 4; ++n) {
            int row = wc + n * 16 + fr;
            offB[s][n] = row * BK + (((s * 4 + hi) ^ (fr & 7)) * 8);
        }
    }

    // staging: per 64-row round, thread t covers phys 16B chunk t within the
    // 8 KB round; row_in_round = wid*8 + lane/8 (row&7 == lane>>3), source
    // column pre-swizzled: chunk = (lane&7) ^ (lane>>3).
    const int srow = wid * 8 + (lane >> 3);
    const int scol = ((lane & 7) ^ (lane >> 3)) * 8;
    const ushort* aSrc = A + (size_t)(brow + srow) * K + scol;
    const ushort* bSrc = B + (size_t)(bcol + srow) * K + scol;
    const int stDst = wid * 512;   // wave-uniform LDS chunk (HW adds lane*16B)

    floatx4 acc[4][4];
#pragma unroll
    for (int m = 0; m < 4; ++m)
#pragma unroll
        for (int n = 0; n < 4; ++n) acc[m][n] = (floatx4)0.0f;

    auto STAGE = [&](int koff, int bufsel) {
        ushort* da = As + bufsel * A_TILE + stDst;
        ushort* db = Bs + bufsel * B_TILE + stDst;
        const ushort* sa = aSrc + koff;
        const ushort* sb = bSrc + koff;
        gload_lds16(sa,                   da);
        gload_lds16(sa + (size_t)64  * K, da + 4096);
        gload_lds16(sa + (size_t)128 * K, da + 8192);
        gload_lds16(sa + (size_t)192 * K, da + 12288);
        gload_lds16(sb,                   db);
        gload_lds16(sb + (size_t)64  * K, db + 4096);
    };

    auto COMPUTE = [&](int bufsel) {
        const ushort* pA = As + bufsel * A_TILE;
        const ushort* pB = Bs + bufsel * B_TILE;
#pragma unroll
        for (int s = 0; s < 2; ++s) {
            bf16x8 af[4], bf[4];
#pragma unroll
            for (int m = 0; m < 4; ++m)
                af[m] = *(const bf16x8*)(pA + offA[s][m]);
#pragma unroll
            for (int n = 0; n < 4; ++n)
                bf[n] = *(const bf16x8*)(pB + offB[s][n]);
            __builtin_amdgcn_s_setprio(1);
#pragma unroll
            for (int m = 0; m < 4; ++m)
#pragma unroll
                for (int n = 0; n < 4; ++n)
                    acc[m][n] = __builtin_amdgcn_mfma_f32_16x16x32_bf16(
                        af[m], bf[n], acc[m][n], 0, 0, 0);
            __builtin_amdgcn_s_setprio(0);
        }
    };

    const int nK = K / BK;   // caller guarantees >= 2

    STAGE(0, 0);
    STAGE(BK, 1);
    asm volatile("s_waitcnt vmcnt(6)" ::: "memory");   // tile 0 landed
    __builtin_amdgcn_s_barrier();
    asm volatile("" ::: "memory");

    for (int kt = 0; kt < nK - 2; ++kt) {
        COMPUTE(kt & 1);
        asm volatile("" ::: "memory");
        __builtin_amdgcn_s_barrier();          // all waves done reading buf
        asm volatile("" ::: "memory");
        STAGE((kt + 2) * BK, kt & 1);
        asm volatile("s_waitcnt vmcnt(6)" ::: "memory");  // tile kt+1 landed
        __builtin_amdgcn_s_barrier();
        asm volatile("" ::: "memory");
    }
    // tail: tiles nK-2, nK-1 (no more staging)
    COMPUTE((nK - 2) & 1);
    asm volatile("s_waitcnt vmcnt(0)" ::: "memory");   // tile nK-1 landed
    __builtin_amdgcn_s_barrier();
    asm volatile("" ::: "memory");
    COMPUTE((nK - 1) & 1);

    // epilogue: C/D layout col=lane&15, row=hi*4+j  [m89/m91 verified]
    float al[4], bi[4];
    const int ccol = bcol + wc + fr;
#pragma unroll
    for (int n = 0; n < 4; ++n) {
        al[n] = alpha[ccol + n * 16];
        bi[n] = bias[ccol + n * 16];
    }
    const int r0 = brow + wr + hi * 4;
#pragma unroll
    for (int m = 0; m < 4; ++m)
#pragma unroll
        for (int n = 0; n < 4; ++n)
#pragma unroll
            for (int j = 0; j < 4; ++j) {
                int row = r0 + m * 16 + j;
                int col = ccol + n * 16;
                C[(size_t)row * N + col] = acc[m][n][j] * al[n] + bi[n];
            }
}

// ---------------- safety fallback (fp32 vector, naive) ----------------------
__global__ void gemm_f32_naive(const float* __restrict__ A,
                               const float* __restrict__ B,
                               const float* __restrict__ scale,
                               const float* __restrict__ mean,
                               const float* __restrict__ var,
                               const float* __restrict__ gamma,
                               const float* __restrict__ beta,
                               float* __restrict__ C, int N, int K) {
    int o = blockIdx.x * blockDim.x + threadIdx.x;
    int b = blockIdx.y;
    if (o >= N) return;
    float s = 0.f;
    const float* a = A + (size_t)b * K;
    const float* w = B + (size_t)o * K;
    for (int k = 0; k < K; ++k) s += a[k] * w[k];
    float rs = rsqrtf(var[o] + EPS);
    float g = gamma[o] * rs;
    C[(size_t)b * N + o] = s * scale[o] * g + (beta[o] - mean[o] * g);
}

extern "C" void kernel_launch(void* const* d_in, const int* in_sizes, int n_in,
                              void* d_out, int out_size, void* d_ws, size_t ws_size,
                              hipStream_t stream) {
    const float* x     = (const float*)d_in[0];
    const float* w     = (const float*)d_in[1];
    const float* scale = (const float*)d_in[2];
    const float* mean  = (const float*)d_in[3];
    const float* var   = (const float*)d_in[4];
    const float* gamma = (const float*)d_in[5];
    const float* beta  = (const float*)d_in[6];
    float* out = (float*)d_out;

    const int OUT = in_sizes[2];
    const int IN  = in_sizes[1] / OUT;
    const int Bsz = in_sizes[0] / IN;

    const size_t xElems = (size_t)Bsz * IN;
    const size_t wElems = (size_t)OUT * IN;
    const size_t need = xElems * 2 + wElems * 2 + (size_t)OUT * 8;

    const bool tiled_ok = (Bsz % BM == 0) && (OUT % BN == 0) &&
                          (IN % BK == 0) && (IN / BK >= 2) &&
                          (ws_size >= need);

    if (!tiled_ok) {
        dim3 grid((OUT + 255) / 256, Bsz);
        gemm_f32_naive<<<grid, 256, 0, stream>>>(x, w, scale, mean, var, gamma,
                                                 beta, out, OUT, IN);
        return;
    }

    ushort* xb = (ushort*)d_ws;
    ushort* wb = xb + xElems;
    float* alpha = (float*)(wb + wElems);
    float* bias  = alpha + OUT;

    cvt_f32_to_bf16<<<2048, 256, 0, stream>>>(x, xb, (int)(xElems / 4));
    cvt_f32_to_bf16<<<2048, 256, 0, stream>>>(w, wb, (int)(wElems / 4));
    bn_fold<<<(OUT + 255) / 256, 256, 0, stream>>>(scale, mean, var, gamma, beta,
                                                   alpha, bias, OUT);

    dim3 grid((Bsz / BM) * (OUT / BN));
    gemm_bf16_bn<<<grid, 512, 0, stream>>>(xb, wb, alpha, bias, out, Bsz, OUT, IN);
}

// Round 4
// 58.278 us; speedup vs baseline: 1.2799x; 1.1199x over previous
//
#include <hip/hip_runtime.h>
#include <hip/hip_bf16.h>

typedef __bf16 bf16x8 __attribute__((ext_vector_type(8)));
typedef float floatx4 __attribute__((ext_vector_type(4)));

#define BM 256
#define BN 128
#define BK 64
#define A_TILE (BM * BK)   // 16384 ushorts = 32 KB
#define B_TILE (BN * BK)   // 8192 ushorts  = 16 KB
#define EPS 1e-5f

// ---------------- f32 -> bf16 conversion (vectorized, grid-stride) ----------
__global__ void cvt_f32_to_bf16(const float* __restrict__ in,
                                ushort* __restrict__ out, int n4) {
    int i = blockIdx.x * blockDim.x + threadIdx.x;
    int stride = gridDim.x * blockDim.x;
    for (; i < n4; i += stride) {
        float4 v = reinterpret_cast<const float4*>(in)[i];
        ushort4 o;
        o.x = __builtin_bit_cast(unsigned short, __float2bfloat16(v.x));
        o.y = __builtin_bit_cast(unsigned short, __float2bfloat16(v.y));
        o.z = __builtin_bit_cast(unsigned short, __float2bfloat16(v.z));
        o.w = __builtin_bit_cast(unsigned short, __float2bfloat16(v.w));
        reinterpret_cast<ushort4*>(out)[i] = o;
    }
}

// ---------------- fold BN+scale into per-column alpha/bias ------------------
__global__ void bn_fold(const float* __restrict__ scale,
                        const float* __restrict__ mean,
                        const float* __restrict__ var,
                        const float* __restrict__ gamma,
                        const float* __restrict__ beta,
                        float* __restrict__ alpha,
                        float* __restrict__ bias, int n) {
    int i = blockIdx.x * blockDim.x + threadIdx.x;
    if (i < n) {
        float rs = rsqrtf(var[i] + EPS);
        float g = gamma[i] * rs;
        alpha[i] = scale[i] * g;
        bias[i]  = beta[i] - mean[i] * g;
    }
}

__device__ __forceinline__ void gload_lds16(const ushort* g, ushort* l) {
    __builtin_amdgcn_global_load_lds(
        (const __attribute__((address_space(1))) void*)g,
        (__attribute__((address_space(3))) void*)l, 16, 0, 0);
}

// ---------------- bf16 MFMA GEMM: 256x128 tile, BK=64, depth-3 pipeline -----
// C[m][n] = sum_k A[m][k]*B[n][k]; epilogue C = C*alpha[n] + bias[n].
//
// 3 LDS buffers (144 KB), prefetch depth 3, 18 loads in flight, vmcnt(12).
// Per iter kt (buffers rotate cur = kt%3):
//   ds_read all 16 b128 fragments of tile kt   (from buf cur)
//   s_waitcnt lgkmcnt(0)                        // own reads complete
//   s_barrier                                   // ALL waves done reading cur
//   STAGE(kt+3 -> cur)                          // outstanding 12 -> 18
//   MFMA x32 (setprio 1)                        // overlaps load flight time
//   s_waitcnt vmcnt(12)                         // own tile kt+1 loads landed
//   s_barrier                                   // all waves' kt+1 landed
// Issue-to-wait gap for a tile's loads ~2.5 compute phases -> covers L3/HBM
// latency (the R2 depth-2 version paid ~3000 cyc/iter of latency stall).
//
// LDS swizzle (T2, rule #21 both-sides): logical tile [R][64] bf16, row =
// 128 B = 8 chunks of 16 B. phys chunk = logical chunk ^ (row&7). Staging
// pre-swizzles the GLOBAL source column (global_load_lds writes linearly);
// fragment reads apply the same XOR. R2 measured: bank conflicts = 0.
__global__ __launch_bounds__(512, 2) void gemm_bf16_bn(
    const ushort* __restrict__ A,   // [M][K] bf16 bits
    const ushort* __restrict__ B,   // [N][K] bf16 bits
    const float* __restrict__ alpha,
    const float* __restrict__ bias,
    float* __restrict__ C, int M, int N, int K) {
    __shared__ ushort As[3 * A_TILE];   // 96 KB
    __shared__ ushort Bs[3 * B_TILE];   // 48 KB

    const int tid  = threadIdx.x;
    const int wid  = tid >> 6;
    const int lane = tid & 63;

    // bijective XCD-aware block swizzle (m204)
    const int nwg  = (int)gridDim.x;
    const int orig = (int)blockIdx.x;
    const int q = nwg >> 3, rr = nwg & 7;
    const int xcd = orig & 7;
    const int swz = ((xcd < rr) ? xcd * (q + 1) : rr * (q + 1) + (xcd - rr) * q)
                    + (orig >> 3);
    const int nTilesN = N / BN;
    const int brow = (swz / nTilesN) * BM;
    const int bcol = (swz % nTilesN) * BN;

    // 8 waves = 4M x 2N, each owns a 64x64 output sub-tile
    const int wr = (wid >> 1) * 64;
    const int wc = (wid & 1) * 64;
    const int fr = lane & 15;
    const int hi = lane >> 4;

    // fragment LDS offsets (ushort units), loop-invariant, swizzled
    int offA[2][4], offB[2][4];
#pragma unroll
    for (int s = 0; s < 2; ++s) {
#pragma unroll
        for (int m = 0; m < 4; ++m) {
            int row = wr + m * 16 + fr;                  // row&7 == fr&7
            offA[s][m] = row * BK + (((s * 4 + hi) ^ (fr & 7)) * 8);
        }
#pragma unroll
        for (int n = 0; n < 4; ++n) {
            int row = wc + n * 16 + fr;
            offB[s][n] = row * BK + (((s * 4 + hi) ^ (fr & 7)) * 8);
        }
    }

    // staging: per 64-row round, thread t covers phys 16B chunk t within the
    // 8 KB round; row_in_round = wid*8 + lane/8 (row&7 == lane>>3), source
    // column pre-swizzled: chunk = (lane&7) ^ (lane>>3).
    const int srow = wid * 8 + (lane >> 3);
    const int scol = ((lane & 7) ^ (lane >> 3)) * 8;
    const ushort* aSrc = A + (size_t)(brow + srow) * K + scol;
    const ushort* bSrc = B + (size_t)(bcol + srow) * K + scol;
    const int stDst = wid * 512;   // wave-uniform LDS chunk (HW adds lane*16B)

    floatx4 acc[4][4];
#pragma unroll
    for (int m = 0; m < 4; ++m)
#pragma unroll
        for (int n = 0; n < 4; ++n) acc[m][n] = (floatx4)0.0f;

    auto STAGE = [&](int koff, int bufsel) {
        ushort* da = As + bufsel * A_TILE + stDst;
        ushort* db = Bs + bufsel * B_TILE + stDst;
        const ushort* sa = aSrc + koff;
        const ushort* sb = bSrc + koff;
        gload_lds16(sa,                   da);
        gload_lds16(sa + (size_t)64  * K, da + 4096);
        gload_lds16(sa + (size_t)128 * K, da + 8192);
        gload_lds16(sa + (size_t)192 * K, da + 12288);
        gload_lds16(sb,                   db);
        gload_lds16(sb + (size_t)64  * K, db + 4096);
    };

    auto LOADFRAG = [&](int bufsel, bf16x8 af[2][4], bf16x8 bf[2][4]) {
        const ushort* pA = As + bufsel * A_TILE;
        const ushort* pB = Bs + bufsel * B_TILE;
#pragma unroll
        for (int s = 0; s < 2; ++s) {
#pragma unroll
            for (int m = 0; m < 4; ++m)
                af[s][m] = *(const bf16x8*)(pA + offA[s][m]);
#pragma unroll
            for (int n = 0; n < 4; ++n)
                bf[s][n] = *(const bf16x8*)(pB + offB[s][n]);
        }
    };

    auto DOMFMA = [&](bf16x8 af[2][4], bf16x8 bf[2][4]) {
        __builtin_amdgcn_s_setprio(1);
#pragma unroll
        for (int s = 0; s < 2; ++s)
#pragma unroll
            for (int m = 0; m < 4; ++m)
#pragma unroll
                for (int n = 0; n < 4; ++n)
                    acc[m][n] = __builtin_amdgcn_mfma_f32_16x16x32_bf16(
                        af[s][m], bf[s][n], acc[m][n], 0, 0, 0);
        __builtin_amdgcn_s_setprio(0);
    };

    const int nK = K / BK;   // caller guarantees >= 4

    STAGE(0, 0);
    STAGE(BK, 1);
    STAGE(2 * BK, 2);
    asm volatile("s_waitcnt vmcnt(12)" ::: "memory");   // tile 0 landed (own)
    __builtin_amdgcn_s_barrier();                       // all waves' tile 0
    asm volatile("" ::: "memory");

    int cur = 0;
    for (int kt = 0; kt < nK - 3; ++kt) {
        bf16x8 af[2][4], bf[2][4];
        LOADFRAG(cur, af, bf);
        asm volatile("s_waitcnt lgkmcnt(0)" ::: "memory");  // own reads done
        __builtin_amdgcn_s_barrier();            // all waves done reading cur
        asm volatile("" ::: "memory");
        STAGE((kt + 3) * BK, cur);               // overwrite cur with tile kt+3
        DOMFMA(af, bf);
        asm volatile("s_waitcnt vmcnt(12)" ::: "memory");   // tile kt+1 landed
        __builtin_amdgcn_s_barrier();
        asm volatile("" ::: "memory");
        cur = (cur == 2) ? 0 : cur + 1;
    }
    // tail: tiles nK-3, nK-2, nK-1 (no more staging)
    {
        bf16x8 af[2][4], bf[2][4];
        LOADFRAG(cur, af, bf);
        DOMFMA(af, bf);
        asm volatile("s_waitcnt vmcnt(6)" ::: "memory");    // tile nK-2 landed
        __builtin_amdgcn_s_barrier();
        asm volatile("" ::: "memory");
        cur = (cur == 2) ? 0 : cur + 1;
    }
    {
        bf16x8 af[2][4], bf[2][4];
        LOADFRAG(cur, af, bf);
        DOMFMA(af, bf);
        asm volatile("s_waitcnt vmcnt(0)" ::: "memory");    // tile nK-1 landed
        __builtin_amdgcn_s_barrier();
        asm volatile("" ::: "memory");
        cur = (cur == 2) ? 0 : cur + 1;
    }
    {
        bf16x8 af[2][4], bf[2][4];
        LOADFRAG(cur, af, bf);
        DOMFMA(af, bf);
    }

    // epilogue: C/D layout col=lane&15, row=hi*4+j  [m89/m91 verified]
    float al[4], bi[4];
    const int ccol = bcol + wc + fr;
#pragma unroll
    for (int n = 0; n < 4; ++n) {
        al[n] = alpha[ccol + n * 16];
        bi[n] = bias[ccol + n * 16];
    }
    const int r0 = brow + wr + hi * 4;
#pragma unroll
    for (int m = 0; m < 4; ++m)
#pragma unroll
        for (int n = 0; n < 4; ++n)
#pragma unroll
            for (int j = 0; j < 4; ++j) {
                int row = r0 + m * 16 + j;
                int col = ccol + n * 16;
                C[(size_t)row * N + col] = acc[m][n][j] * al[n] + bi[n];
            }
}

// ---------------- safety fallback (fp32 vector, naive) ----------------------
__global__ void gemm_f32_naive(const float* __restrict__ A,
                               const float* __restrict__ B,
                               const float* __restrict__ scale,
                               const float* __restrict__ mean,
                               const float* __restrict__ var,
                               const float* __restrict__ gamma,
                               const float* __restrict__ beta,
                               float* __restrict__ C, int N, int K) {
    int o = blockIdx.x * blockDim.x + threadIdx.x;
    int b = blockIdx.y;
    if (o >= N) return;
    float s = 0.f;
    const float* a = A + (size_t)b * K;
    const float* w = B + (size_t)o * K;
    for (int k = 0; k < K; ++k) s += a[k] * w[k];
    float rs = rsqrtf(var[o] + EPS);
    float g = gamma[o] * rs;
    C[(size_t)b * N + o] = s * scale[o] * g + (beta[o] - mean[o] * g);
}

extern "C" void kernel_launch(void* const* d_in, const int* in_sizes, int n_in,
                              void* d_out, int out_size, void* d_ws, size_t ws_size,
                              hipStream_t stream) {
    const float* x     = (const float*)d_in[0];
    const float* w     = (const float*)d_in[1];
    const float* scale = (const float*)d_in[2];
    const float* mean  = (const float*)d_in[3];
    const float* var   = (const float*)d_in[4];
    const float* gamma = (const float*)d_in[5];
    const float* beta  = (const float*)d_in[6];
    float* out = (float*)d_out;

    const int OUT = in_sizes[2];
    const int IN  = in_sizes[1] / OUT;
    const int Bsz = in_sizes[0] / IN;

    const size_t xElems = (size_t)Bsz * IN;
    const size_t wElems = (size_t)OUT * IN;
    const size_t need = xElems * 2 + wElems * 2 + (size_t)OUT * 8;

    const bool tiled_ok = (Bsz % BM == 0) && (OUT % BN == 0) &&
                          (IN % BK == 0) && (IN / BK >= 4) &&
                          (ws_size >= need);

    if (!tiled_ok) {
        dim3 grid((OUT + 255) / 256, Bsz);
        gemm_f32_naive<<<grid, 256, 0, stream>>>(x, w, scale, mean, var, gamma,
                                                 beta, out, OUT, IN);
        return;
    }

    ushort* xb = (ushort*)d_ws;
    ushort* wb = xb + xElems;
    float* alpha = (float*)(wb + wElems);
    float* bias  = alpha + OUT;

    cvt_f32_to_bf16<<<2048, 256, 0, stream>>>(x, xb, (int)(xElems / 4));
    cvt_f32_to_bf16<<<2048, 256, 0, stream>>>(w, wb, (int)(wElems / 4));
    bn_fold<<<(OUT + 255) / 256, 256, 0, stream>>>(scale, mean, var, gamma, beta,
                                                   alpha, bias, OUT);

    dim3 grid((Bsz / BM) * (OUT / BN));
    gemm_bf16_bn<<<grid, 512, 0, stream>>>(xb, wb, alpha, bias, out, Bsz, OUT, IN);
}